// Round 1
// baseline (2821.838 us; speedup 1.0000x reference)
//
#include <hip/hip_runtime.h>
#include <hip/hip_bf16.h>
#include <cstdint>

#define DIMX   128
#define N_REL  6
#define N_BASES 30
#define N_HERB 5000
#define KAGG   768   // N_REL*DIM
#define KTOT   896   // (N_REL+1)*DIM
#define KSC    512   // scorer feat dim
#define BN     64
#define KT     16

// ---------------- counting / prep ----------------

__global__ void k_count(const int* __restrict__ ei, const int* __restrict__ et,
                        int E, int* __restrict__ cnt) {
    int e = blockIdx.x * blockDim.x + threadIdx.x;
    if (e >= E) return;
    int dst = ei[E + e];
    int t   = et[e];
    atomicAdd(&cnt[dst * N_REL + t], 1);
}

__global__ void k_invcnt(const int* __restrict__ cnt, float* __restrict__ inv, int n) {
    int i = blockIdx.x * blockDim.x + threadIdx.x;
    if (i >= n) return;
    int c = cnt[i];
    inv[i] = 1.0f / (float)(c > 0 ? c : 1);
}

// Wall[k][o], k in [0,896): rows r*128+d hold W_r[d][o] = sum_b comp[r,b]*basis[b,d,o];
// rows 768+d hold root[d][o].
__global__ void k_buildW(const float* __restrict__ basis, const float* __restrict__ comp,
                         const float* __restrict__ root, float* __restrict__ Wall) {
    int b = blockIdx.x;          // 0..895 (7*128)
    int r = b >> 7, d = b & 127;
    int o = threadIdx.x;
    if (r < N_REL) {
        float acc = 0.f;
        #pragma unroll
        for (int bb = 0; bb < N_BASES; ++bb)
            acc += comp[r * N_BASES + bb] * basis[((size_t)bb * DIMX + d) * DIMX + o];
        Wall[((size_t)r * DIMX + d) * DIMX + o] = acc;
    } else {
        Wall[((size_t)KAGG + d) * DIMX + o] = root[(size_t)d * DIMX + o];
    }
}

// ---------------- edge scatter: agg[dst][rel][:] += x[src][:] ----------------
// 32 threads per edge, float4 each, 4 scalar f32 HW atomics.

__global__ __launch_bounds__(256)
void k_scatter(const int* __restrict__ ei, const int* __restrict__ et,
               const float* __restrict__ x, int E, float* __restrict__ agg) {
    unsigned gid = blockIdx.x * blockDim.x + threadIdx.x;
    int e = (int)(gid >> 5);
    if (e >= E) return;
    int q = (int)(gid & 31);
    int src = ei[e];
    int dst = ei[E + e];
    int t   = et[e];
    float4 v = *(const float4*)(x + (size_t)src * DIMX + q * 4);
    float* base = agg + ((size_t)dst * N_REL + t) * DIMX + q * 4;
    unsafeAtomicAdd(base + 0, v.x);
    unsafeAtomicAdd(base + 1, v.y);
    unsafeAtomicAdd(base + 2, v.z);
    unsafeAtomicAdd(base + 3, v.w);
}

// ---------------- node-transform GEMM ----------------
// out[n][o] = bias[o] + sum_{k<768} (agg[n][k]*invcnt[n][k>>7]) * Wall[k][o]
//                     + sum_{k>=768} x[n][k-768] * Wall[k][o]
// Block: 64 nodes x 128 outs. 256 threads, each 8 nodes x 4 outs.

__global__ __launch_bounds__(256)
void k_gemm_nodes(const float* __restrict__ agg, const float* __restrict__ invcnt,
                  const float* __restrict__ x, const float* __restrict__ Wall,
                  const float* __restrict__ bias, float* __restrict__ out,
                  int nTotal, int relu) {
    __shared__ float As[BN][KT];
    __shared__ float Ws[KT][DIMX];
    int tid = threadIdx.x;
    int n0 = blockIdx.x * BN;

    int lrow = tid >> 2;             // 0..63 node row for loads
    int lk4  = (tid & 3) * 4;        // 0,4,8,12
    int ng = n0 + lrow; if (ng >= nTotal) ng = nTotal - 1;

    int oc = (tid & 31) * 4;         // output col base
    int nb = (tid >> 5) * 8;         // node base within tile

    float acc[8][4];
    #pragma unroll
    for (int i = 0; i < 8; ++i)
        #pragma unroll
        for (int j = 0; j < 4; ++j) acc[i][j] = 0.f;

    for (int k0 = 0; k0 < KTOT; k0 += KT) {
        int k = k0 + lk4;
        float4 av;
        if (k < KAGG) {
            av = *(const float4*)(agg + (size_t)ng * KAGG + k);
            float s = invcnt[ng * N_REL + (k >> 7)];
            av.x *= s; av.y *= s; av.z *= s; av.w *= s;
        } else {
            av = *(const float4*)(x + (size_t)ng * DIMX + (k - KAGG));
        }
        *(float4*)&As[lrow][lk4] = av;

        const float4* wsrc = (const float4*)(Wall + (size_t)k0 * DIMX);
        ((float4*)Ws)[tid]       = wsrc[tid];
        ((float4*)Ws)[tid + 256] = wsrc[tid + 256];
        __syncthreads();

        #pragma unroll
        for (int kk = 0; kk < KT; kk += 4) {
            float4 wv0 = *(float4*)&Ws[kk + 0][oc];
            float4 wv1 = *(float4*)&Ws[kk + 1][oc];
            float4 wv2 = *(float4*)&Ws[kk + 2][oc];
            float4 wv3 = *(float4*)&Ws[kk + 3][oc];
            #pragma unroll
            for (int i = 0; i < 8; ++i) {
                float4 a4 = *(float4*)&As[nb + i][kk];
                acc[i][0] += a4.x * wv0.x + a4.y * wv1.x + a4.z * wv2.x + a4.w * wv3.x;
                acc[i][1] += a4.x * wv0.y + a4.y * wv1.y + a4.z * wv2.y + a4.w * wv3.y;
                acc[i][2] += a4.x * wv0.z + a4.y * wv1.z + a4.z * wv2.z + a4.w * wv3.z;
                acc[i][3] += a4.x * wv0.w + a4.y * wv1.w + a4.z * wv2.w + a4.w * wv3.w;
            }
        }
        __syncthreads();
    }

    float4 bv = *(const float4*)(bias + oc);
    #pragma unroll
    for (int i = 0; i < 8; ++i) {
        int n = n0 + nb + i;
        if (n < nTotal) {
            float4 r;
            r.x = acc[i][0] + bv.x;
            r.y = acc[i][1] + bv.y;
            r.z = acc[i][2] + bv.z;
            r.w = acc[i][3] + bv.w;
            if (relu) {
                r.x = fmaxf(r.x, 0.f); r.y = fmaxf(r.y, 0.f);
                r.z = fmaxf(r.z, 0.f); r.w = fmaxf(r.w, 0.f);
            }
            *(float4*)(out + (size_t)n * DIMX + oc) = r;
        }
    }
}

// ---------------- scorer GEMM: hid = relu(feat @ sw1 + sb1) ----------------
// feat[n][k] built on the fly: q=k>>7: h, p, h*p, |h-p|.

__global__ __launch_bounds__(256)
void k_scorer_gemm(const float* __restrict__ x2, const int* __restrict__ h_idx,
                   const int* __restrict__ p_idx, const float* __restrict__ sw1,
                   const float* __restrict__ sb1, float* __restrict__ hid, int P) {
    __shared__ float As[BN][KT];
    __shared__ float Ws[KT][DIMX];
    int tid = threadIdx.x;
    int n0 = blockIdx.x * BN;

    int lrow = tid >> 2;
    int lk4  = (tid & 3) * 4;
    int ng = n0 + lrow; if (ng >= P) ng = P - 1;
    int hrow = h_idx[ng];
    int prow = N_HERB + p_idx[ng];

    int oc = (tid & 31) * 4;
    int nb = (tid >> 5) * 8;

    float acc[8][4];
    #pragma unroll
    for (int i = 0; i < 8; ++i)
        #pragma unroll
        for (int j = 0; j < 4; ++j) acc[i][j] = 0.f;

    for (int k0 = 0; k0 < KSC; k0 += KT) {
        int k = k0 + lk4;
        int q = k >> 7;
        int d = k & 127;
        float4 hv = *(const float4*)(x2 + (size_t)hrow * DIMX + d);
        float4 pv = *(const float4*)(x2 + (size_t)prow * DIMX + d);
        float4 av;
        if (q == 0)      av = hv;
        else if (q == 1) av = pv;
        else if (q == 2) { av.x = hv.x * pv.x; av.y = hv.y * pv.y;
                           av.z = hv.z * pv.z; av.w = hv.w * pv.w; }
        else             { av.x = fabsf(hv.x - pv.x); av.y = fabsf(hv.y - pv.y);
                           av.z = fabsf(hv.z - pv.z); av.w = fabsf(hv.w - pv.w); }
        *(float4*)&As[lrow][lk4] = av;

        const float4* wsrc = (const float4*)(sw1 + (size_t)k0 * DIMX);
        ((float4*)Ws)[tid]       = wsrc[tid];
        ((float4*)Ws)[tid + 256] = wsrc[tid + 256];
        __syncthreads();

        #pragma unroll
        for (int kk = 0; kk < KT; kk += 4) {
            float4 wv0 = *(float4*)&Ws[kk + 0][oc];
            float4 wv1 = *(float4*)&Ws[kk + 1][oc];
            float4 wv2 = *(float4*)&Ws[kk + 2][oc];
            float4 wv3 = *(float4*)&Ws[kk + 3][oc];
            #pragma unroll
            for (int i = 0; i < 8; ++i) {
                float4 a4 = *(float4*)&As[nb + i][kk];
                acc[i][0] += a4.x * wv0.x + a4.y * wv1.x + a4.z * wv2.x + a4.w * wv3.x;
                acc[i][1] += a4.x * wv0.y + a4.y * wv1.y + a4.z * wv2.y + a4.w * wv3.y;
                acc[i][2] += a4.x * wv0.z + a4.y * wv1.z + a4.z * wv2.z + a4.w * wv3.z;
                acc[i][3] += a4.x * wv0.w + a4.y * wv1.w + a4.z * wv2.w + a4.w * wv3.w;
            }
        }
        __syncthreads();
    }

    float4 bv = *(const float4*)(sb1 + oc);
    #pragma unroll
    for (int i = 0; i < 8; ++i) {
        int n = n0 + nb + i;
        if (n < P) {
            float4 r;
            r.x = fmaxf(acc[i][0] + bv.x, 0.f);
            r.y = fmaxf(acc[i][1] + bv.y, 0.f);
            r.z = fmaxf(acc[i][2] + bv.z, 0.f);
            r.w = fmaxf(acc[i][3] + bv.w, 0.f);
            *(float4*)(hid + (size_t)n * DIMX + oc) = r;
        }
    }
}

// ---------------- scorer final dot: out = hid @ sw2 + sb2 ----------------

__global__ void k_scorer_out(const float* __restrict__ hid, const float* __restrict__ sw2,
                             const float* __restrict__ sb2, float* __restrict__ out, int P) {
    int tid = blockIdx.x * blockDim.x + threadIdx.x;
    int wave = tid >> 6;
    int lane = tid & 63;
    int half = lane >> 5, l32 = lane & 31;
    int pair = wave * 2 + half;
    if (pair >= P) return;
    float4 hv = *(const float4*)(hid + (size_t)pair * DIMX + l32 * 4);
    float4 wv = *(const float4*)(sw2 + l32 * 4);
    float s = hv.x * wv.x + hv.y * wv.y + hv.z * wv.z + hv.w * wv.w;
    #pragma unroll
    for (int off = 16; off; off >>= 1) s += __shfl_xor(s, off, 64);
    if (l32 == 0) out[pair] = s + sb2[0];
}

// ---------------- launcher ----------------

extern "C" void kernel_launch(void* const* d_in, const int* in_sizes, int n_in,
                              void* d_out, int out_size, void* d_ws, size_t ws_size,
                              hipStream_t stream) {
    const int*   ei       = (const int*)d_in[0];
    const int*   et       = (const int*)d_in[1];
    const int*   h_idx    = (const int*)d_in[2];
    const int*   p_idx    = (const int*)d_in[3];
    const float* node_emb = (const float*)d_in[4];
    const float* basis1   = (const float*)d_in[5];
    const float* comp1    = (const float*)d_in[6];
    const float* root1    = (const float*)d_in[7];
    const float* bias1    = (const float*)d_in[8];
    const float* basis2   = (const float*)d_in[9];
    const float* comp2    = (const float*)d_in[10];
    const float* root2    = (const float*)d_in[11];
    const float* bias2    = (const float*)d_in[12];
    const float* sw1      = (const float*)d_in[13];
    const float* sb1      = (const float*)d_in[14];
    const float* sw2      = (const float*)d_in[15];
    const float* sb2      = (const float*)d_in[16];
    float* out = (float*)d_out;

    int E  = in_sizes[1];
    int P  = in_sizes[2];
    int NN = in_sizes[4] / DIMX;   // 60000

    // workspace layout (floats)
    float* agg  = (float*)d_ws;                                   // NN*768
    float* hid  = agg;                                            // alias, used after layer GEMMs
    int*   cnt  = (int*)(agg + (size_t)NN * KAGG);                // NN*6
    float* invc = (float*)(cnt + (size_t)NN * N_REL);             // NN*6
    float* x1   = invc + (size_t)NN * N_REL;                      // NN*128
    float* x2   = x1 + (size_t)NN * DIMX;                         // NN*128
    float* Wall = x2 + (size_t)NN * DIMX;                         // 896*128

    size_t aggBytes = (size_t)NN * KAGG * sizeof(float);

    hipMemsetAsync(cnt, 0, (size_t)NN * N_REL * sizeof(int), stream);
    hipMemsetAsync(agg, 0, aggBytes, stream);

    k_count<<<(E + 255) / 256, 256, 0, stream>>>(ei, et, E, cnt);
    k_invcnt<<<(NN * N_REL + 255) / 256, 256, 0, stream>>>(cnt, invc, NN * N_REL);

    // layer 1
    k_buildW<<<KTOT, DIMX, 0, stream>>>(basis1, comp1, root1, Wall);
    k_scatter<<<(E * 32 + 255) / 256, 256, 0, stream>>>(ei, et, node_emb, E, agg);
    k_gemm_nodes<<<(NN + BN - 1) / BN, 256, 0, stream>>>(agg, invc, node_emb, Wall, bias1, x1, NN, 1);

    // layer 2
    hipMemsetAsync(agg, 0, aggBytes, stream);
    k_buildW<<<KTOT, DIMX, 0, stream>>>(basis2, comp2, root2, Wall);
    k_scatter<<<(E * 32 + 255) / 256, 256, 0, stream>>>(ei, et, x1, E, agg);
    k_gemm_nodes<<<(NN + BN - 1) / BN, 256, 0, stream>>>(agg, invc, x1, Wall, bias2, x2, NN, 0);

    // scorer
    k_scorer_gemm<<<(P + BN - 1) / BN, 256, 0, stream>>>(x2, h_idx, p_idx, sw1, sb1, hid, P);
    k_scorer_out<<<(P * 32 + 255) / 256, 256, 0, stream>>>(hid, sw2, sb2, out, P);
}